// Round 6
// baseline (143.899 us; speedup 1.0000x reference)
//
#include <hip/hip_runtime.h>
#include <hip/hip_bf16.h>
#include <stdint.h>

#define N_RES 256
#define CMDIM 256

typedef __attribute__((ext_vector_type(8))) short bf16x8;
typedef __attribute__((ext_vector_type(4))) float f32x4;
typedef __attribute__((ext_vector_type(2))) unsigned int u32x2;

__device__ __forceinline__ unsigned short f32_to_bf16(float f) {
    union { float f; unsigned int u; } v; v.f = f;
    unsigned int u = v.u;
    return (unsigned short)((u + 0x7FFFu + ((u >> 16) & 1u)) >> 16);
}

// Layouts (bf16):
//  B2f (j,d rows, frag-linear): elem(row=j*32+d, s) ->
//      ((row>>4)*4 + (s>>5))*512 + ((s>>3)&3)*128 + (row&15)*8 + (s&7)
//  Wbf (LN-proj weights, frag-linear): elem(ch, cm) ->
//      ((ch>>4)*8 + (cm>>5))*512 + ((cm>>3)&3)*128 + (ch&15)*8 + (cm&7)
//  A3 (a-side keyed by i-pair P=i>>1 and c-block cb): elem(i, c=cb*8+cloc, s) ->
//      ((P*4+cb)*4 + (s>>5))*512 + ((s>>3)&3)*128 + ((i&1)*8+cloc)*8 + (s&7)
//  wof2 (wo keyed to o's stored chunk order cs=dq*8+cloc, k=(cb*8+cloc)*32+dq*8+e):
//      (((zo>>4)*4+cb)*8 + (cs>>2))*512 + (cs&3)*128 + (zo&15)*8 + e
// Every MFMA fragment load is one coalesced 1 KB global_load_dwordx4.

// ---------------- K0: convert + repack weights ----------------
__global__ __launch_bounds__(256) void k_prep(
    const float* __restrict__ w1, const float* __restrict__ w2,
    const float* __restrict__ wo,
    unsigned short* __restrict__ Wbf, unsigned short* __restrict__ wof2)
{
    int t = blockIdx.x * 256 + threadIdx.x;
    if (t < 16384) {
        int ch = t >> 8, cm = t & 255;
        float v = (ch < 32) ? w1[ch * 256 + cm] : w2[(ch - 32) * 256 + cm];
        int addr = ((ch >> 4) * 8 + (cm >> 5)) * 512 + ((cm >> 3) & 3) * 128 + (ch & 15) * 8 + (cm & 7);
        Wbf[addr] = f32_to_bf16(v);
    }
    if (t < 131072) {
        int zo = t >> 10, k = t & 1023;
        int cb = k >> 8, cloc = (k >> 5) & 7, dq = (k >> 3) & 3, e = k & 7;
        int cs = dq * 8 + cloc;
        int addr = (((zo >> 4) * 4 + cb) * 8 + (cs >> 2)) * 512 + (cs & 3) * 128 + (zo & 15) * 8 + e;
        wof2[addr] = f32_to_bf16(wo[t]);
    }
}

// ---------------- K1: LayerNorm + dual projection ----------------
// 1024 WGs: b = i*4 + sblk. LN 32 rows, MFMA D[64ch][32s] = W*mn^T.
// A-part epilogue stages for the A3 layout; B-part keeps frag-linear B2f.
__global__ __launch_bounds__(256) void k_ln_proj(
    const float* __restrict__ m, const float* __restrict__ lnw, const float* __restrict__ lnb,
    const float* __restrict__ b1, const float* __restrict__ b2,
    const unsigned short* __restrict__ Wbf,
    unsigned short* __restrict__ A3, unsigned short* __restrict__ B2f)
{
    __shared__ unsigned short mn[32 * 256];   // 16 KB
    __shared__ unsigned short stg[2048];      // 4 KB: [0,1024) A-part [g][c][e]; [1024,2048) B-part frag-linear
    int b = blockIdx.x;
    int i = b >> 2, sblk = b & 3;
    int tid = threadIdx.x;
    int wv = tid >> 6, lane = tid & 63;
    int quad = lane >> 4, l15 = lane & 15;

    f32x4 lw = *(const f32x4*)(lnw + lane * 4);
    f32x4 lb = *(const f32x4*)(lnb + lane * 4);

    #pragma unroll
    for (int r = 0; r < 8; ++r) {
        int sl = wv * 8 + r;
        int s = sblk * 32 + sl;
        const float* row = m + ((size_t)s * N_RES + i) * CMDIM;
        f32x4 x = *(const f32x4*)(row + lane * 4);
        float s1 = x[0] + x[1] + x[2] + x[3];
        float s2 = x[0]*x[0] + x[1]*x[1] + x[2]*x[2] + x[3]*x[3];
        #pragma unroll
        for (int off = 32; off; off >>= 1) {
            s1 += __shfl_xor(s1, off);
            s2 += __shfl_xor(s2, off);
        }
        float mu = s1 * (1.0f / 256.0f);
        float var = s2 * (1.0f / 256.0f) - mu * mu;
        float rstd = rsqrtf(var + 1e-5f);
        float n0 = (x[0] - mu) * rstd * lw[0] + lb[0];
        float n1 = (x[1] - mu) * rstd * lw[1] + lb[1];
        float n2 = (x[2] - mu) * rstd * lw[2] + lb[2];
        float n3 = (x[3] - mu) * rstd * lw[3] + lb[3];
        unsigned int p0 = (unsigned)f32_to_bf16(n0) | ((unsigned)f32_to_bf16(n1) << 16);
        unsigned int p1 = (unsigned)f32_to_bf16(n2) | ((unsigned)f32_to_bf16(n3) << 16);
        int chunk = lane >> 1;
        int pos = (chunk & 16) | ((chunk ^ sl) & 15);
        unsigned int* dst = (unsigned int*)((char*)mn + sl * 512 + pos * 16 + (lane & 1) * 8);
        dst[0] = p0; dst[1] = p1;
    }
    __syncthreads();

    bf16x8 af[8];
    #pragma unroll
    for (int ks = 0; ks < 8; ++ks)
        af[ks] = *(const bf16x8*)(Wbf + (wv * 8 + ks) * 512 + lane * 8);

    f32x4 acc[2];
    acc[0] = (f32x4){0.f, 0.f, 0.f, 0.f};
    acc[1] = (f32x4){0.f, 0.f, 0.f, 0.f};
    #pragma unroll
    for (int ks = 0; ks < 8; ++ks) {
        #pragma unroll
        for (int nb = 0; nb < 2; ++nb) {
            int sl = nb * 16 + l15;
            int chunk = ks * 4 + quad;
            int pos = (chunk & 16) | ((chunk ^ sl) & 15);
            bf16x8 bf = *(const bf16x8*)((char*)mn + sl * 512 + pos * 16);
            acc[nb] = __builtin_amdgcn_mfma_f32_16x16x32_bf16(af[ks], bf, acc[nb], 0, 0, 0);
        }
    }

    const float* bsrc = (wv < 2) ? b1 : b2;
    f32x4 bias = *(const f32x4*)(bsrc + (wv & 1) * 16 + quad * 4);
    if (wv < 2) {
        // A-part: stg[(g*32 + c)*8 + e], g = sl>>3, e = sl&7, c in [0,32)
        #pragma unroll
        for (int nb = 0; nb < 2; ++nb) {
            int sl = nb * 16 + l15;
            int g = sl >> 3, e = sl & 7;
            #pragma unroll
            for (int reg = 0; reg < 4; ++reg) {
                int c = (wv & 1) * 16 + quad * 4 + reg;
                stg[(g * 32 + c) * 8 + e] = f32_to_bf16(acc[nb][reg] + bias[reg]);
            }
        }
    } else {
        unsigned short* sbase = stg + 1024 + (wv & 1) * 512 + quad * 32;
        #pragma unroll
        for (int nb = 0; nb < 2; ++nb) {
            int sl = nb * 16 + l15;
            int soff = ((sl >> 3) & 3) * 128 + (sl & 7);
            #pragma unroll
            for (int reg = 0; reg < 4; ++reg)
                sbase[soff + reg * 8] = f32_to_bf16(acc[nb][reg] + bias[reg]);
        }
    }
    __syncthreads();

    if (tid < 128) {
        int q = (tid >> 3) & 3, cb = tid >> 5, cloc = tid & 7;
        int P = i >> 1;
        bf16x8 v = *(const bf16x8*)(stg + (q * 32 + cb * 8 + cloc) * 8);
        *(bf16x8*)(A3 + ((size_t)((P * 4 + cb) * 4 + sblk)) * 512 + q * 128 + ((i & 1) * 8 + cloc) * 8) = v;
    } else {
        int blk = (tid >> 6) & 1, l = tid & 63;
        bf16x8 v = *(const bf16x8*)(stg + tid * 8);
        *(bf16x8*)(B2f + ((size_t)((i * 2 + blk) * 4 + sblk)) * 512 + l * 8) = v;
    }
}

// ---------------- K2: c-blocked fused GEMM1+GEMM2 ----------------
// WG = 8i x 8j = 64 pairs, 1024 WGs. Loop cb=0..3: stage A computes
// o-partial[64 pairs][256 k=(8c x 32d)] into obuf (double-buffered 2x32 KB);
// stage B contracts with wo k-slice, z accumulates in registers (K=1024 total).
// B-side (j,d) fragments held in registers across the whole kernel.
// o LDS: addr = pair*512 + phys*16 + (within 8B halves), stored chunk
// cs = dq*8 + cloc, phys = cs ^ (pair&7).
__global__ __launch_bounds__(256, 2) void k_fused2(
    const unsigned short* __restrict__ A3, const unsigned short* __restrict__ B2f,
    const unsigned short* __restrict__ wof2, const float* __restrict__ bo,
    float* __restrict__ out)
{
    __shared__ char obuf[2][32768];
    int bx = blockIdx.x;               // 8 i's: i0 = bx*8
    int by = blockIdx.y;               // 8 j's: j0 = by*8
    int tid = threadIdx.x, wv = tid >> 6, lane = tid & 63;
    int quad = lane >> 4, l15 = lane & 15;

    // persistent: B-side fragments (wave's 64 m-rows of 256)
    bf16x8 am[4][4];
    #pragma unroll
    for (int mb = 0; mb < 4; ++mb)
        #pragma unroll
        for (int ks = 0; ks < 4; ++ks)
            am[mb][ks] = *(const bf16x8*)(B2f + (size_t)((by * 16 + wv * 4 + mb) * 4 + ks) * 512 + lane * 8);

    f32x4 accZ[2][4];
    #pragma unroll
    for (int a = 0; a < 2; ++a)
        #pragma unroll
        for (int b = 0; b < 4; ++b) accZ[a][b] = (f32x4){0.f, 0.f, 0.f, 0.f};

    for (int ph = 0; ph < 5; ++ph) {
        if (ph < 4) {
            int cb = ph;
            char* ob = obuf[ph & 1];
            #pragma unroll
            for (int np = 0; np < 2; ++np) {
                bf16x8 bn[2][4];
                #pragma unroll
                for (int nn = 0; nn < 2; ++nn)
                    #pragma unroll
                    for (int ks = 0; ks < 4; ++ks)
                        bn[nn][ks] = *(const bf16x8*)(A3 + (size_t)(((bx * 4 + np * 2 + nn) * 4 + cb) * 4 + ks) * 512 + lane * 8);
                f32x4 accA[4][2];
                #pragma unroll
                for (int a = 0; a < 4; ++a)
                    #pragma unroll
                    for (int b = 0; b < 2; ++b) accA[a][b] = (f32x4){0.f, 0.f, 0.f, 0.f};
                #pragma unroll
                for (int ks = 0; ks < 4; ++ks)
                    #pragma unroll
                    for (int mb = 0; mb < 4; ++mb)
                        #pragma unroll
                        for (int nn = 0; nn < 2; ++nn)
                            accA[mb][nn] = __builtin_amdgcn_mfma_f32_16x16x32_bf16(am[mb][ks], bn[nn][ks], accA[mb][nn], 0, 0, 0);
                // write o-partial: m = wv*64 + mb*16 + quad*4 + reg = (jl,d); n = (il,cloc)
                #pragma unroll
                for (int mb = 0; mb < 4; ++mb) {
                    int jl = wv * 2 + (mb >> 1);
                    int d0 = (mb & 1) * 16 + quad * 4;
                    int dq = d0 >> 3, half = (d0 >> 2) & 1;
                    #pragma unroll
                    for (int nn = 0; nn < 2; ++nn) {
                        int nb = np * 2 + nn;
                        int il = nb * 2 + (l15 >> 3);
                        int cloc = l15 & 7;
                        int pair = il * 8 + jl;
                        int cs = dq * 8 + cloc;
                        int phys = cs ^ (pair & 7);
                        f32x4 a4 = accA[mb][nn];
                        unsigned int p0 = (unsigned)f32_to_bf16(a4[0]) | ((unsigned)f32_to_bf16(a4[1]) << 16);
                        unsigned int p1 = (unsigned)f32_to_bf16(a4[2]) | ((unsigned)f32_to_bf16(a4[3]) << 16);
                        u32x2 pv = {p0, p1};
                        *(u32x2*)(ob + pair * 512 + phys * 16 + half * 8) = pv;
                    }
                }
            }
        }
        if (ph > 0) {
            int cb = ph - 1;
            const char* ob = obuf[cb & 1];
            #pragma unroll
            for (int kt = 0; kt < 8; ++kt) {
                bf16x8 af2[2], bfr[4];
                #pragma unroll
                for (int zb = 0; zb < 2; ++zb)
                    af2[zb] = *(const bf16x8*)(wof2 + (size_t)((((wv * 2 + zb) * 4 + cb) * 8 + kt)) * 512 + lane * 8);
                #pragma unroll
                for (int pb = 0; pb < 4; ++pb) {
                    int pair = pb * 16 + l15;
                    int cs = kt * 4 + quad;
                    int phys = cs ^ (pair & 7);
                    bfr[pb] = *(const bf16x8*)(ob + pair * 512 + phys * 16);
                }
                #pragma unroll
                for (int zb = 0; zb < 2; ++zb)
                    #pragma unroll
                    for (int pb = 0; pb < 4; ++pb)
                        accZ[zb][pb] = __builtin_amdgcn_mfma_f32_16x16x32_bf16(af2[zb], bfr[pb], accZ[zb][pb], 0, 0, 0);
            }
        }
        __syncthreads();
    }

    // epilogue: z = (accZ + bo) / n_seq
    #pragma unroll
    for (int zb = 0; zb < 2; ++zb) {
        int zo = wv * 32 + zb * 16 + quad * 4;
        f32x4 b4 = *(const f32x4*)(bo + zo);
        #pragma unroll
        for (int pb = 0; pb < 4; ++pb) {
            int pair = pb * 16 + l15;
            int i = bx * 8 + (pair >> 3);
            int j = by * 8 + (pair & 7);
            f32x4 v;
            #pragma unroll
            for (int reg = 0; reg < 4; ++reg)
                v[reg] = (accZ[zb][pb][reg] + b4[reg]) * (1.0f / 128.0f);
            *(f32x4*)(out + ((size_t)(i * 256 + j)) * 128 + zo) = v;
        }
    }
}

extern "C" void kernel_launch(void* const* d_in, const int* in_sizes, int n_in,
                              void* d_out, int out_size, void* d_ws, size_t ws_size,
                              hipStream_t stream) {
    const float* m   = (const float*)d_in[0];
    const float* lnw = (const float*)d_in[1];
    const float* lnb = (const float*)d_in[2];
    const float* w1  = (const float*)d_in[3];
    const float* b1  = (const float*)d_in[4];
    const float* w2  = (const float*)d_in[5];
    const float* b2  = (const float*)d_in[6];
    const float* wo  = (const float*)d_in[7];
    const float* bo  = (const float*)d_in[8];
    float* out = (float*)d_out;
    char* ws = (char*)d_ws;

    unsigned short* Wbf  = (unsigned short*)(ws);                            // 32 KB
    unsigned short* wof2 = (unsigned short*)(ws + 32768);                    // 256 KB
    unsigned short* A3   = (unsigned short*)(ws + 32768 + 262144);           // 2 MB
    unsigned short* B2f  = (unsigned short*)(ws + 32768 + 262144 + 2097152); // 2 MB

    hipLaunchKernelGGL(k_prep, dim3(512), dim3(256), 0, stream, w1, w2, wo, Wbf, wof2);
    hipLaunchKernelGGL(k_ln_proj, dim3(1024), dim3(256), 0, stream,
                       m, lnw, lnb, b1, b2, Wbf, A3, B2f);
    hipLaunchKernelGGL(k_fused2, dim3(32, 32), dim3(256), 0, stream,
                       A3, B2f, wof2, bo, out);
}